// Round 6
// baseline (127.127 us; speedup 1.0000x reference)
//
#include <hip/hip_runtime.h>
#include <cstdint>

// MMCL loss: per-row top-K hard negatives.
// M=4096 rows, N=13000 cols fp32; K = int(0.01*(N-1)) = 129.
// loss_row = 5*(1-pos)^2 + mean_{topK negatives}((1+v)^2); output = mean over rows.
//
// One 256-thread block per row. Streaming pass (4x-unrolled, hoisted loads):
// per element just compare>t0; matches (~2.3%) append to a per-wave LDS
// segment (LDS atomic counter) AND bump a 256-bucket value histogram
// (bucket = clamp((x-2)*64)). Selection: one wave suffix-scans the histogram
// (shfl only), picks the bucket holding the K-th largest negative + rank
// `need`; the bucket's few elements are gathered and exact T rank-selected
// from raw values. Positive column streams like any value and is exactly
// removed via uniform corrections (hist / rank / final sum).
// loss = [sum_{v>T}(1+v)^2 + (K-cnt)*(1+T)^2]/K (exact under ties = lax.top_k).
// Fallbacks (never taken for this data, kept for exactness): bucket-overflow
// -> 8-pass 4-bit radix select; candidate under/overflow -> threshold
// bisection in sortable-key space. Final mean fused via per-block atomicAdd.

constexpr int M_ROWS = 4096;
constexpr int N_COLS = 13000;
constexpr int N4     = N_COLS / 4;        // 3250 float4s (13000 % 4 == 0)
constexpr int KSEL   = 129;               // int(0.01 * 12999)
constexpr int BLOCK  = 256;
constexpr int NWAVE  = BLOCK / 64;        // 4
constexpr int WCAP   = 320;               // per-wave candidate cap (~74 expected)
constexpr int GCAP   = 64;                // bucket-gather cap (~5-11 expected)
constexpr int FULL_IT  = N4 / (4 * BLOCK);        // 3
constexpr int TAIL_BASE = FULL_IT * 4 * BLOCK;    // 3072
constexpr int TAIL_N    = N4 - TAIL_BASE;         // 178
constexpr float DELTA_C = 5.0f;
constexpr float T0   = 2.0f;

// monotone float -> uint32 key (larger float => larger key)
__device__ __forceinline__ uint32_t f2key(float f) {
    uint32_t u = __float_as_uint(f);
    return u ^ ((u & 0x80000000u) ? 0xFFFFFFFFu : 0x80000000u);
}
__device__ __forceinline__ float key2f(uint32_t k) {
    uint32_t u = (k & 0x80000000u) ? (k ^ 0x80000000u) : ~k;
    return __uint_as_float(u);
}
__device__ __forceinline__ int bucketof(float x) {
    int i = (int)((x - 2.0f) * 64.0f);
    return i < 0 ? 0 : (i > 255 ? 255 : i);
}

__global__ void zero_out(float* out) { if (threadIdx.x == 0) out[0] = 0.0f; }

__global__ __launch_bounds__(BLOCK, 8) void row_loss_kernel(
    const float* __restrict__ inputs,
    const int*   __restrict__ targets,
    float*       __restrict__ out)
{
    __shared__ float cand[NWAVE * WCAP];   // per-wave segments
    __shared__ int   s_wcnt[NWAVE];
    __shared__ int   s_hist[256];          // value-bucket hist (first 16 reused by fallback)
    __shared__ float s_gath[GCAP];
    __shared__ int   s_gcnt;
    __shared__ int   s_bkt, s_need;
    __shared__ float s_T;
    __shared__ float s_fpart[NWAVE];
    __shared__ int   s_ipart[NWAVE];
    __shared__ int   s_rb, s_rn;           // fallback radix bucket/need

    const int row  = blockIdx.x;
    const int tid  = threadIdx.x;
    const int wid  = tid >> 6;
    const int lane = tid & 63;
    const float* rp = inputs + (size_t)row * N_COLS;
    const float4* rp4 = reinterpret_cast<const float4*>(rp);
    const int pos = targets[row];
    const float pos_v = rp[pos];           // uniform broadcast load
    float* wseg = cand + wid * WCAP;

    // ---- streaming: candidates + value-histogram (common: one pass, t=2) ----
    uint32_t keyA = 0u, keyB = 0xFFFFFFFFu;
    float t = T0;
    bool collapsed = false;
    float Tval = 0.0f;
    int c0, c1, c2, c3;

    for (int iter = 0; iter < 64; ++iter) {
        s_hist[tid] = 0;                       // BLOCK==256: one bucket each
        if (tid < NWAVE) s_wcnt[tid] = 0;
        __syncthreads();

        auto proc = [&](float x) {             // rare-match path only
            if (x > t) {
                atomicAdd(&s_hist[bucketof(x)], 1);
                const int slot = atomicAdd(&s_wcnt[wid], 1);
                if (slot < WCAP) wseg[slot] = x;
            }
        };
        for (int it = 0; it < FULL_IT; ++it) {
            const int b = it * 4 * BLOCK + tid;
            const float4 v0 = rp4[b];
            const float4 v1 = rp4[b +     BLOCK];
            const float4 v2 = rp4[b + 2 * BLOCK];
            const float4 v3 = rp4[b + 3 * BLOCK];
            proc(v0.x); proc(v0.y); proc(v0.z); proc(v0.w);
            proc(v1.x); proc(v1.y); proc(v1.z); proc(v1.w);
            proc(v2.x); proc(v2.y); proc(v2.z); proc(v2.w);
            proc(v3.x); proc(v3.y); proc(v3.z); proc(v3.w);
        }
        if (tid < TAIL_N) {
            const float4 vt = rp4[TAIL_BASE + tid];
            proc(vt.x); proc(vt.y); proc(vt.z); proc(vt.w);
        }
        __syncthreads();

        c0 = s_wcnt[0]; c1 = s_wcnt[1]; c2 = s_wcnt[2]; c3 = s_wcnt[3];
        const int total = c0 + c1 + c2 + c3;
        const bool ovf = (c0 > WCAP) | (c1 > WCAP) | (c2 > WCAP) | (c3 > WCAP);
        const int npos = (pos_v > t) ? 1 : 0;

        if (collapsed || (!ovf && (total - npos) >= KSEL)) break;

        const uint32_t kt = f2key(t);
        if (ovf) keyA = kt; else keyB = kt;
        if (keyB - keyA <= 1u) {
            Tval = key2f(keyB);      // exact: #{x > Tval} < K <= #{x >= Tval}
            t = Tval;
            collapsed = true;
        } else {
            t = key2f(keyA + (keyB - keyA) / 2u);
        }
        __syncthreads();             // protect s_hist/s_wcnt re-zeroing
    }

    const int cw = (wid == 0) ? c0 : (wid == 1) ? c1 : (wid == 2) ? c2 : c3;
    const int mycnt = cw < WCAP ? cw : WCAP;   // wave-uniform
    const uint32_t key_pos = f2key(pos_v);
    const bool pos_in = (pos_v > t);

    float T;
    if (collapsed) {
        T = Tval;
    } else {
        // ---- pick bucket b containing the K-th largest negative (1 wave) ----
        if (wid == 0) {
            if (lane == 0) s_gcnt = 0;
            int h[4];
            #pragma unroll
            for (int k = 0; k < 4; ++k) {
                h[k] = s_hist[4 * lane + k];
                if (pos_in && bucketof(pos_v) == 4 * lane + k) h[k] -= 1;
            }
            const int G = h[0] + h[1] + h[2] + h[3];
            int x = G;                        // inclusive suffix sum over lanes
            #pragma unroll
            for (int off = 1; off < 64; off <<= 1) {
                const int tmp = __shfl_down(x, off);
                if (lane + off < 64) x += tmp;
            }
            const int xnext = x - G;          // C(4*lane+4)
            const int cc3 = xnext + h[3];
            const int cc2 = cc3 + h[2];
            const int cc1 = cc2 + h[1];
            // x == cc1 + h[0] == C(4*lane)
            if (x >= KSEL && xnext < KSEL) {  // exactly one lane
                int k, Cnext;
                if      (cc3 >= KSEL) { k = 3; Cnext = xnext; }
                else if (cc2 >= KSEL) { k = 2; Cnext = cc3; }
                else if (cc1 >= KSEL) { k = 1; Cnext = cc2; }
                else                  { k = 0; Cnext = cc1; }
                s_bkt = 4 * lane + k;
                s_need = KSEL - Cnext;
            }
        }
        __syncthreads();
        const int bsel = s_bkt;
        const int need = s_need;

        // ---- gather bucket-b elements from this wave's segment ----
        for (int c = lane; c < mycnt; c += 64) {
            const float x = wseg[c];
            if (bucketof(x) == bsel) {
                const int slot = atomicAdd(&s_gcnt, 1);
                if (slot < GCAP) s_gath[slot] = x;
            }
        }
        __syncthreads();
        const int m = s_gcnt;

        if (m <= GCAP) {
            // ---- exact rank-select of T among <=64 raw values (1 wave) ----
            if (wid == 0) {
                int skip = -1;
                if (pos_in && bucketof(pos_v) == bsel) {
                    const bool eq = (lane < m) &&
                        (__float_as_uint(s_gath[lane]) == __float_as_uint(pos_v));
                    const uint64_t em = __ballot(eq);
                    if (em) skip = __ffsll((long long)em) - 1;
                }
                const bool valid = (lane < m) && (lane != skip);
                const float x = valid ? s_gath[lane] : 0.0f;
                int g = 0, ge = 0;
                for (int j = 0; j < m; ++j) {
                    const float y = s_gath[j];       // broadcast read
                    const bool vj = (j != skip);
                    g  += (vj && y >  x);
                    ge += (vj && y >= x);
                }
                if (valid && g < need && ge >= need) s_T = x;
            }
            __syncthreads();
            T = s_T;
        } else {
            // ---- fallback: 8-pass 4-bit radix select over segments ----
            uint32_t hi = 0;
            int need2 = KSEL;
            for (int shift = 28; shift >= 0; shift -= 4) {
                if (tid < 16) s_hist[tid] = 0;
                __syncthreads();
                const uint32_t maskHigh = (uint32_t)(0xFFFFFFFFull << (shift + 4));
                for (int c = lane; c < mycnt; c += 64) {
                    const uint32_t k = f2key(wseg[c]);
                    if ((k & maskHigh) == hi)
                        atomicAdd(&s_hist[(k >> shift) & 15], 1);
                }
                __syncthreads();
                if (tid == 0) {
                    if (pos_in && ((key_pos & maskHigh) == hi))
                        s_hist[(key_pos >> shift) & 15] -= 1;
                    int cum = 0, b = 15;
                    for (; b > 0; --b) {
                        const int h = s_hist[b];
                        if (cum + h >= need2) break;
                        cum += h;
                    }
                    s_rb = b;
                    s_rn = need2 - cum;
                }
                __syncthreads();
                hi |= ((uint32_t)s_rb) << shift;
                need2 = s_rn;
            }
            T = key2f(hi);
        }
    }

    // ---- sum f(v)=(1+v)^2 over v > T, pad with (K-cnt) copies of f(T) ----
    float s = 0.0f;
    int g = 0;
    for (int c = lane; c < mycnt; c += 64) {
        const float x = wseg[c];
        if (x > T) { const float u = 1.0f + x; s += u * u; ++g; }
    }
    #pragma unroll
    for (int off = 32; off > 0; off >>= 1) {
        s += __shfl_down(s, off);
        g += __shfl_down(g, off);
    }
    if (lane == 0) { s_fpart[wid] = s; s_ipart[wid] = g; }
    __syncthreads();
    if (tid == 0) {
        float ss = s_fpart[0] + s_fpart[1] + s_fpart[2] + s_fpart[3];
        int   gg = s_ipart[0] + s_ipart[1] + s_ipart[2] + s_ipart[3];
        if (pos_in && pos_v > T) {     // exact removal of the positive column
            const float u = 1.0f + pos_v;
            ss -= u * u;
            gg -= 1;
        }
        const float uT = 1.0f + T;
        const float neg = (ss + (float)(KSEL - gg) * uT * uT) / (float)KSEL;
        const float d = 1.0f - pos_v;
        const float loss = DELTA_C * d * d + neg;
        atomicAdd(out, loss * (1.0f / (float)M_ROWS));
    }
}

extern "C" void kernel_launch(void* const* d_in, const int* in_sizes, int n_in,
                              void* d_out, int out_size, void* d_ws, size_t ws_size,
                              hipStream_t stream) {
    const float* inputs  = (const float*)d_in[0];
    // d_in[1] = targets_ (unused by reference), d_in[3] = GT_MC (unused)
    const int*   targets = (const int*)d_in[2];
    float* out = (float*)d_out;

    zero_out<<<1, 64, 0, stream>>>(out);
    row_loss_kernel<<<M_ROWS, BLOCK, 0, stream>>>(inputs, targets, out);
}

// Round 7
// 74.688 us; speedup vs baseline: 1.7021x; 1.7021x over previous
//
#include <hip/hip_runtime.h>
#include <cstdint>

// MMCL loss: per-row top-K hard negatives.
// M=4096 rows, N=13000 cols fp32; K = int(0.01*(N-1)) = 129.
// loss_row = 5*(1-pos)^2 + mean_{topK negatives}((1+v)^2); output = mean over rows.
//
// One 256-thread block per row.
// Streaming (R4-proven): 4x-unrolled, 4 float4 loads hoisted per iter,
// candidates > t0=2.0 (~296/row for N(0,1)) ballot-compacted into per-wave
// LDS segments (wave-uniform counter, no atomics in the hot loop).
// Selection (new): one post-stream pass builds a 256-bucket value histogram
// (bucket = clamp((x-2)*64)) from the segments (~75 atomics/wave); one wave
// suffix-scans it (shfl only) to find the bucket holding the K-th largest
// negative + rank; that bucket's few elements are gathered and exact T is
// rank-selected from raw values. ~6 barriers total.
// The positive column streams like any value and is exactly removed via
// uniform corrections (histogram / rank-skip / final sum).
// loss = [sum_{v>T}(1+v)^2 + (K-cnt)*(1+T)^2]/K (exact under ties = lax.top_k).
// Fallbacks (never taken for this data, kept for exactness): gather overflow
// -> 8-pass 4-bit radix select; segment under/overflow -> threshold bisection
// in sortable-key space. Final mean fused via per-block atomicAdd.

constexpr int M_ROWS = 4096;
constexpr int N_COLS = 13000;
constexpr int N4     = N_COLS / 4;        // 3250 float4s (13000 % 4 == 0)
constexpr int KSEL   = 129;               // int(0.01 * 12999)
constexpr int BLOCK  = 256;
constexpr int NWAVE  = BLOCK / 64;        // 4
constexpr int WCAP   = 320;               // per-wave candidate cap (~74 expected)
constexpr int GCAP   = 64;                // bucket-gather cap (~5-11 expected)
constexpr int FULL_IT  = N4 / (4 * BLOCK);        // 3
constexpr int TAIL_BASE = FULL_IT * 4 * BLOCK;    // 3072
constexpr int TAIL_N    = N4 - TAIL_BASE;         // 178
constexpr float DELTA_C = 5.0f;
constexpr float T0   = 2.0f;

// monotone float -> uint32 key (larger float => larger key)
__device__ __forceinline__ uint32_t f2key(float f) {
    uint32_t u = __float_as_uint(f);
    return u ^ ((u & 0x80000000u) ? 0xFFFFFFFFu : 0x80000000u);
}
__device__ __forceinline__ float key2f(uint32_t k) {
    uint32_t u = (k & 0x80000000u) ? (k ^ 0x80000000u) : ~k;
    return __uint_as_float(u);
}
__device__ __forceinline__ int bucketof(float x) {
    int i = (int)((x - 2.0f) * 64.0f);
    return i < 0 ? 0 : (i > 255 ? 255 : i);
}

__global__ void zero_out(float* out) { if (threadIdx.x == 0) out[0] = 0.0f; }

__global__ __launch_bounds__(BLOCK) void row_loss_kernel(
    const float* __restrict__ inputs,
    const int*   __restrict__ targets,
    float*       __restrict__ out)
{
    __shared__ float cand[NWAVE * WCAP];   // per-wave segments
    __shared__ int   s_wcnt[NWAVE];
    __shared__ int   s_hist[256];          // value-bucket hist (16 reused by fallback)
    __shared__ float s_gath[GCAP];
    __shared__ int   s_gcnt;
    __shared__ int   s_bkt, s_need;
    __shared__ float s_T;
    __shared__ float s_fpart[NWAVE];
    __shared__ int   s_ipart[NWAVE];
    __shared__ int   s_rb, s_rn;           // fallback radix bucket/need

    const int row  = blockIdx.x;
    const int tid  = threadIdx.x;
    const int wid  = tid >> 6;
    const int lane = tid & 63;
    const float* rp = inputs + (size_t)row * N_COLS;
    const float4* rp4 = reinterpret_cast<const float4*>(rp);
    const int pos = targets[row];
    const float pos_v = rp[pos];           // uniform broadcast load
    const uint64_t below = (1ull << lane) - 1ull;
    float* wseg = cand + wid * WCAP;

    // one full streaming pass at threshold t; returns wave-uniform match count
    auto stream_pass = [&](float t) -> int {
        int wcnt = 0;
        auto proc = [&](float x) {
            const uint64_t m = __ballot(x > t);
            if (m) {                                   // wave-uniform branch
                if (x > t) {
                    const int slot = wcnt + (int)__popcll(m & below);
                    if (slot < WCAP) wseg[slot] = x;
                }
                wcnt += (int)__popcll(m);              // uniform add
            }
        };
        for (int it = 0; it < FULL_IT; ++it) {         // 3 iters
            const int b = it * 4 * BLOCK + tid;
            const float4 v0 = rp4[b];
            const float4 v1 = rp4[b +     BLOCK];
            const float4 v2 = rp4[b + 2 * BLOCK];
            const float4 v3 = rp4[b + 3 * BLOCK];
            proc(v0.x); proc(v0.y); proc(v0.z); proc(v0.w);
            proc(v1.x); proc(v1.y); proc(v1.z); proc(v1.w);
            proc(v2.x); proc(v2.y); proc(v2.z); proc(v2.w);
            proc(v3.x); proc(v3.y); proc(v3.z); proc(v3.w);
        }
        // branchless tail: sentinel keeps ballot wave-uniform, never matches
        const float4 vt = (tid < TAIL_N) ? rp4[TAIL_BASE + tid]
                                         : make_float4(-1e30f, -1e30f, -1e30f, -1e30f);
        proc(vt.x); proc(vt.y); proc(vt.z); proc(vt.w);
        return wcnt;
    };

    // ---- candidate collection (common case: one pass at t = 2.0) ----
    uint32_t keyA = 0u, keyB = 0xFFFFFFFFu;
    float t = T0;
    bool collapsed = false;       // K-th largest negative known exactly (Tval)
    float Tval = 0.0f;
    int cnt = 0;                  // this wave's candidate count (uniform)

    for (int iter = 0; iter < 64; ++iter) {
        cnt = stream_pass(t);
        if (lane == 0) s_wcnt[wid] = cnt;
        __syncthreads();
        const int c0 = s_wcnt[0], c1 = s_wcnt[1], c2 = s_wcnt[2], c3 = s_wcnt[3];
        __syncthreads();
        const int total = c0 + c1 + c2 + c3;
        const bool ovf = (c0 > WCAP) | (c1 > WCAP) | (c2 > WCAP) | (c3 > WCAP);
        const int npos = (pos_v > t) ? 1 : 0;   // positive inside candidates?

        if (collapsed || (!ovf && (total - npos) >= KSEL)) break;

        const uint32_t kt = f2key(t);
        if (ovf) keyA = kt; else keyB = kt;
        if (keyB - keyA <= 1u) {
            Tval = key2f(keyB);      // exact: #{x > Tval} < K <= #{x >= Tval}
            t = Tval;
            collapsed = true;
            continue;
        }
        t = key2f(keyA + (keyB - keyA) / 2u);
    }

    const int mycnt = cnt < WCAP ? cnt : WCAP;     // wave-uniform
    const uint32_t key_pos = f2key(pos_v);
    const bool pos_in = (pos_v > t);   // positive present in candidate multiset

    float T;
    if (collapsed) {
        T = Tval;   // candidates are exactly {v > T}, negative count < K
    } else {
        // ---- build 256-bucket value histogram from segments (one pass) ----
        s_hist[tid] = 0;                  // BLOCK==256: one bucket each
        if (tid == 0) s_gcnt = 0;
        __syncthreads();
        for (int c = lane; c < mycnt; c += 64)     // wave scans own segment
            atomicAdd(&s_hist[bucketof(wseg[c])], 1);
        __syncthreads();

        // ---- pick bucket holding the K-th largest negative (1 wave) ----
        if (wid == 0) {
            int h[4];
            #pragma unroll
            for (int k = 0; k < 4; ++k) {
                h[k] = s_hist[4 * lane + k];
                if (pos_in && bucketof(pos_v) == 4 * lane + k) h[k] -= 1;
            }
            const int G = h[0] + h[1] + h[2] + h[3];
            int x = G;                        // inclusive suffix sum over lanes
            #pragma unroll
            for (int off = 1; off < 64; off <<= 1) {
                const int tmp = __shfl_down(x, off);
                if (lane + off < 64) x += tmp;
            }
            const int xnext = x - G;          // suffix starting at 4*lane+4
            const int cc3 = xnext + h[3];
            const int cc2 = cc3 + h[2];
            const int cc1 = cc2 + h[1];
            if (x >= KSEL && xnext < KSEL) {  // exactly one lane hits this
                int k, Cnext;
                if      (cc3 >= KSEL) { k = 3; Cnext = xnext; }
                else if (cc2 >= KSEL) { k = 2; Cnext = cc3; }
                else if (cc1 >= KSEL) { k = 1; Cnext = cc2; }
                else                  { k = 0; Cnext = cc1; }
                s_bkt = 4 * lane + k;
                s_need = KSEL - Cnext;        // rank within bucket, from top
            }
        }
        __syncthreads();
        const int bsel = s_bkt;
        const int need = s_need;

        // ---- gather that bucket's elements from all segments ----
        for (int c = lane; c < mycnt; c += 64) {
            const float x = wseg[c];
            if (bucketof(x) == bsel) {
                const int slot = atomicAdd(&s_gcnt, 1);
                if (slot < GCAP) s_gath[slot] = x;
            }
        }
        __syncthreads();
        const int m = s_gcnt;

        if (m <= GCAP) {
            // ---- exact rank-select of T among <=64 raw values (1 wave) ----
            if (wid == 0) {
                int skip = -1;
                if (pos_in && bucketof(pos_v) == bsel) {
                    const bool eq = (lane < m) &&
                        (__float_as_uint(s_gath[lane]) == __float_as_uint(pos_v));
                    const uint64_t em = __ballot(eq);
                    if (em) skip = __ffsll((long long)em) - 1;
                }
                const bool valid = (lane < m) && (lane != skip);
                const float x = valid ? s_gath[lane] : 0.0f;
                int g = 0, ge = 0;
                for (int j = 0; j < m; ++j) {
                    const float y = s_gath[j];       // broadcast read
                    const bool vj = (j != skip);
                    g  += (vj && y >  x);
                    ge += (vj && y >= x);
                }
                if (valid && g < need && ge >= need) s_T = x;  // unique value
            }
            __syncthreads();
            T = s_T;
        } else {
            // ---- fallback: 8-pass 4-bit radix select over segments ----
            uint32_t hi = 0;
            int need2 = KSEL;
            for (int shift = 28; shift >= 0; shift -= 4) {
                if (tid < 16) s_hist[tid] = 0;
                __syncthreads();
                const uint32_t maskHigh = (uint32_t)(0xFFFFFFFFull << (shift + 4));
                for (int c = lane; c < mycnt; c += 64) {
                    const uint32_t k = f2key(wseg[c]);
                    if ((k & maskHigh) == hi)
                        atomicAdd(&s_hist[(k >> shift) & 15], 1);
                }
                __syncthreads();
                if (tid == 0) {
                    if (pos_in && ((key_pos & maskHigh) == hi))
                        s_hist[(key_pos >> shift) & 15] -= 1;
                    int cum = 0, b = 15;
                    for (; b > 0; --b) {
                        const int h = s_hist[b];
                        if (cum + h >= need2) break;
                        cum += h;
                    }
                    s_rb = b;
                    s_rn = need2 - cum;
                }
                __syncthreads();
                hi |= ((uint32_t)s_rb) << shift;
                need2 = s_rn;
            }
            T = key2f(hi);
        }
    }

    // ---- sum f(v)=(1+v)^2 over v > T, pad with (K-cnt) copies of f(T) ----
    float s = 0.0f;
    int g = 0;
    for (int c = lane; c < mycnt; c += 64) {
        const float x = wseg[c];
        if (x > T) { const float u = 1.0f + x; s += u * u; ++g; }
    }
    #pragma unroll
    for (int off = 32; off > 0; off >>= 1) {
        s += __shfl_down(s, off);
        g += __shfl_down(g, off);
    }
    if (lane == 0) { s_fpart[wid] = s; s_ipart[wid] = g; }
    __syncthreads();
    if (tid == 0) {
        float ss = s_fpart[0] + s_fpart[1] + s_fpart[2] + s_fpart[3];
        int   gg = s_ipart[0] + s_ipart[1] + s_ipart[2] + s_ipart[3];
        if (pos_in && pos_v > T) {     // exact removal of the positive column
            const float u = 1.0f + pos_v;
            ss -= u * u;
            gg -= 1;
        }
        const float uT = 1.0f + T;
        const float neg = (ss + (float)(KSEL - gg) * uT * uT) / (float)KSEL;
        const float d = 1.0f - pos_v;
        const float loss = DELTA_C * d * d + neg;
        atomicAdd(out, loss * (1.0f / (float)M_ROWS));
    }
}

extern "C" void kernel_launch(void* const* d_in, const int* in_sizes, int n_in,
                              void* d_out, int out_size, void* d_ws, size_t ws_size,
                              hipStream_t stream) {
    const float* inputs  = (const float*)d_in[0];
    // d_in[1] = targets_ (unused by reference), d_in[3] = GT_MC (unused)
    const int*   targets = (const int*)d_in[2];
    float* out = (float*)d_out;

    zero_out<<<1, 64, 0, stream>>>(out);
    row_loss_kernel<<<M_ROWS, BLOCK, 0, stream>>>(inputs, targets, out);
}

// Round 8
// 42.299 us; speedup vs baseline: 3.0054x; 1.7657x over previous
//
#include <hip/hip_runtime.h>
#include <cstdint>

// MMCL loss: per-row top-K hard negatives.
// M=4096 rows, N=13000 cols fp32; K = int(0.01*(N-1)) = 129.
// loss_row = 5*(1-pos)^2 + mean_{topK negatives}((1+v)^2); output = mean over rows.
//
// One 256-thread block per row.
// Streaming (R4-proven): 4x-unrolled, 4 float4 loads hoisted per iter,
// candidates > t0=2.0 (~296/row for N(0,1)) ballot-compacted into per-wave
// LDS segments (wave-uniform counter, no atomics in the hot loop).
// Selection (R7-proven exact): post-stream 256-bucket value histogram
// (bucket = clamp((x-2)*64)) built from the segments; one wave suffix-scans
// it (shfl only) to locate the bucket holding the K-th largest negative +
// within-bucket rank; bucket elements gathered; exact T rank-selected from
// raw values. Positive column streams like any value and is exactly removed
// via uniform corrections (histogram / rank-skip / final sum).
// loss = [sum_{v>T}(1+v)^2 + (K-cnt)*(1+T)^2]/K (exact under ties = lax.top_k).
// Fallbacks (never taken for this data, kept for exactness): gather overflow
// -> 8-pass 4-bit radix select; segment under/overflow -> threshold bisection
// in sortable-key space.
// Per-row losses go to d_ws; a separate tiny kernel does the deterministic
// mean. (R7 measured: single-address global atomicAdd from 4096 blocks costs
// ~25 us on MI355X cross-XCD — do not fuse the mean via one atomic.)

constexpr int M_ROWS = 4096;
constexpr int N_COLS = 13000;
constexpr int N4     = N_COLS / 4;        // 3250 float4s (13000 % 4 == 0)
constexpr int KSEL   = 129;               // int(0.01 * 12999)
constexpr int BLOCK  = 256;
constexpr int NWAVE  = BLOCK / 64;        // 4
constexpr int WCAP   = 320;               // per-wave candidate cap (~74 expected)
constexpr int GCAP   = 64;                // bucket-gather cap (~5-11 expected)
constexpr int FULL_IT  = N4 / (4 * BLOCK);        // 3
constexpr int TAIL_BASE = FULL_IT * 4 * BLOCK;    // 3072
constexpr int TAIL_N    = N4 - TAIL_BASE;         // 178
constexpr float DELTA_C = 5.0f;
constexpr float T0   = 2.0f;

// monotone float -> uint32 key (larger float => larger key)
__device__ __forceinline__ uint32_t f2key(float f) {
    uint32_t u = __float_as_uint(f);
    return u ^ ((u & 0x80000000u) ? 0xFFFFFFFFu : 0x80000000u);
}
__device__ __forceinline__ float key2f(uint32_t k) {
    uint32_t u = (k & 0x80000000u) ? (k ^ 0x80000000u) : ~k;
    return __uint_as_float(u);
}
__device__ __forceinline__ int bucketof(float x) {
    int i = (int)((x - 2.0f) * 64.0f);
    return i < 0 ? 0 : (i > 255 ? 255 : i);
}

__global__ __launch_bounds__(BLOCK) void row_loss_kernel(
    const float* __restrict__ inputs,
    const int*   __restrict__ targets,
    float*       __restrict__ row_loss)
{
    __shared__ float cand[NWAVE * WCAP];   // per-wave segments
    __shared__ int   s_wcnt[NWAVE];
    __shared__ int   s_hist[256];          // value-bucket hist (16 reused by fallback)
    __shared__ float s_gath[GCAP];
    __shared__ int   s_gcnt;
    __shared__ int   s_bkt, s_need;
    __shared__ float s_T;
    __shared__ float s_fpart[NWAVE];
    __shared__ int   s_ipart[NWAVE];
    __shared__ int   s_rb, s_rn;           // fallback radix bucket/need

    const int row  = blockIdx.x;
    const int tid  = threadIdx.x;
    const int wid  = tid >> 6;
    const int lane = tid & 63;
    const float* rp = inputs + (size_t)row * N_COLS;
    const float4* rp4 = reinterpret_cast<const float4*>(rp);
    const int pos = targets[row];
    const float pos_v = rp[pos];           // uniform broadcast load
    const uint64_t below = (1ull << lane) - 1ull;
    float* wseg = cand + wid * WCAP;

    // one full streaming pass at threshold t; returns wave-uniform match count
    auto stream_pass = [&](float t) -> int {
        int wcnt = 0;
        auto proc = [&](float x) {
            const uint64_t m = __ballot(x > t);
            if (x > t) {
                const int slot = wcnt + (int)__popcll(m & below);
                if (slot < WCAP) wseg[slot] = x;
            }
            wcnt += (int)__popcll(m);                  // wave-uniform add
        };
        for (int it = 0; it < FULL_IT; ++it) {         // 3 iters
            const int b = it * 4 * BLOCK + tid;
            const float4 v0 = rp4[b];
            const float4 v1 = rp4[b +     BLOCK];
            const float4 v2 = rp4[b + 2 * BLOCK];
            const float4 v3 = rp4[b + 3 * BLOCK];
            proc(v0.x); proc(v0.y); proc(v0.z); proc(v0.w);
            proc(v1.x); proc(v1.y); proc(v1.z); proc(v1.w);
            proc(v2.x); proc(v2.y); proc(v2.z); proc(v2.w);
            proc(v3.x); proc(v3.y); proc(v3.z); proc(v3.w);
        }
        // branchless tail: sentinel keeps ballot wave-uniform, never matches
        const float4 vt = (tid < TAIL_N) ? rp4[TAIL_BASE + tid]
                                         : make_float4(-1e30f, -1e30f, -1e30f, -1e30f);
        proc(vt.x); proc(vt.y); proc(vt.z); proc(vt.w);
        return wcnt;
    };

    // ---- candidate collection (common case: one pass at t = 2.0) ----
    uint32_t keyA = 0u, keyB = 0xFFFFFFFFu;
    float t = T0;
    bool collapsed = false;       // K-th largest negative known exactly (Tval)
    float Tval = 0.0f;
    int cnt = 0;                  // this wave's candidate count (uniform)

    for (int iter = 0; iter < 64; ++iter) {
        cnt = stream_pass(t);
        if (lane == 0) s_wcnt[wid] = cnt;
        __syncthreads();
        const int c0 = s_wcnt[0], c1 = s_wcnt[1], c2 = s_wcnt[2], c3 = s_wcnt[3];
        __syncthreads();
        const int total = c0 + c1 + c2 + c3;
        const bool ovf = (c0 > WCAP) | (c1 > WCAP) | (c2 > WCAP) | (c3 > WCAP);
        const int npos = (pos_v > t) ? 1 : 0;   // positive inside candidates?

        if (collapsed || (!ovf && (total - npos) >= KSEL)) break;

        const uint32_t kt = f2key(t);
        if (ovf) keyA = kt; else keyB = kt;
        if (keyB - keyA <= 1u) {
            Tval = key2f(keyB);      // exact: #{x > Tval} < K <= #{x >= Tval}
            t = Tval;
            collapsed = true;
            continue;
        }
        t = key2f(keyA + (keyB - keyA) / 2u);
    }

    const int mycnt = cnt < WCAP ? cnt : WCAP;     // wave-uniform
    const uint32_t key_pos = f2key(pos_v);
    const bool pos_in = (pos_v > t);   // positive present in candidate multiset

    float T;
    if (collapsed) {
        T = Tval;   // candidates are exactly {v > T}, negative count < K
    } else {
        // ---- build 256-bucket value histogram from segments (one pass) ----
        s_hist[tid] = 0;                  // BLOCK==256: one bucket each
        if (tid == 0) s_gcnt = 0;
        __syncthreads();
        for (int c = lane; c < mycnt; c += 64)     // wave scans own segment
            atomicAdd(&s_hist[bucketof(wseg[c])], 1);
        __syncthreads();

        // ---- pick bucket holding the K-th largest negative (1 wave) ----
        if (wid == 0) {
            int h[4];
            #pragma unroll
            for (int k = 0; k < 4; ++k) {
                h[k] = s_hist[4 * lane + k];
                if (pos_in && bucketof(pos_v) == 4 * lane + k) h[k] -= 1;
            }
            const int G = h[0] + h[1] + h[2] + h[3];
            int x = G;                        // inclusive suffix sum over lanes
            #pragma unroll
            for (int off = 1; off < 64; off <<= 1) {
                const int tmp = __shfl_down(x, off);
                if (lane + off < 64) x += tmp;
            }
            const int xnext = x - G;          // suffix starting at 4*lane+4
            const int cc3 = xnext + h[3];
            const int cc2 = cc3 + h[2];
            const int cc1 = cc2 + h[1];
            if (x >= KSEL && xnext < KSEL) {  // exactly one lane hits this
                int k, Cnext;
                if      (cc3 >= KSEL) { k = 3; Cnext = xnext; }
                else if (cc2 >= KSEL) { k = 2; Cnext = cc3; }
                else if (cc1 >= KSEL) { k = 1; Cnext = cc2; }
                else                  { k = 0; Cnext = cc1; }
                s_bkt = 4 * lane + k;
                s_need = KSEL - Cnext;        // rank within bucket, from top
            }
        }
        __syncthreads();
        const int bsel = s_bkt;
        const int need = s_need;

        // ---- gather that bucket's elements from all segments ----
        for (int c = lane; c < mycnt; c += 64) {
            const float x = wseg[c];
            if (bucketof(x) == bsel) {
                const int slot = atomicAdd(&s_gcnt, 1);
                if (slot < GCAP) s_gath[slot] = x;
            }
        }
        __syncthreads();
        const int m = s_gcnt;

        if (m <= GCAP) {
            // ---- exact rank-select of T among <=64 raw values (1 wave) ----
            if (wid == 0) {
                int skip = -1;
                if (pos_in && bucketof(pos_v) == bsel) {
                    const bool eq = (lane < m) &&
                        (__float_as_uint(s_gath[lane]) == __float_as_uint(pos_v));
                    const uint64_t em = __ballot(eq);
                    if (em) skip = __ffsll((long long)em) - 1;
                }
                const bool valid = (lane < m) && (lane != skip);
                const float x = valid ? s_gath[lane] : 0.0f;
                int g = 0, ge = 0;
                for (int j = 0; j < m; ++j) {
                    const float y = s_gath[j];       // broadcast read
                    const bool vj = (j != skip);
                    g  += (vj && y >  x);
                    ge += (vj && y >= x);
                }
                if (valid && g < need && ge >= need) s_T = x;  // unique value
            }
            __syncthreads();
            T = s_T;
        } else {
            // ---- fallback: 8-pass 4-bit radix select over segments ----
            uint32_t hi = 0;
            int need2 = KSEL;
            for (int shift = 28; shift >= 0; shift -= 4) {
                if (tid < 16) s_hist[tid] = 0;
                __syncthreads();
                const uint32_t maskHigh = (uint32_t)(0xFFFFFFFFull << (shift + 4));
                for (int c = lane; c < mycnt; c += 64) {
                    const uint32_t k = f2key(wseg[c]);
                    if ((k & maskHigh) == hi)
                        atomicAdd(&s_hist[(k >> shift) & 15], 1);
                }
                __syncthreads();
                if (tid == 0) {
                    if (pos_in && ((key_pos & maskHigh) == hi))
                        s_hist[(key_pos >> shift) & 15] -= 1;
                    int cum = 0, b = 15;
                    for (; b > 0; --b) {
                        const int h = s_hist[b];
                        if (cum + h >= need2) break;
                        cum += h;
                    }
                    s_rb = b;
                    s_rn = need2 - cum;
                }
                __syncthreads();
                hi |= ((uint32_t)s_rb) << shift;
                need2 = s_rn;
            }
            T = key2f(hi);
        }
    }

    // ---- sum f(v)=(1+v)^2 over v > T, pad with (K-cnt) copies of f(T) ----
    float s = 0.0f;
    int g = 0;
    for (int c = lane; c < mycnt; c += 64) {
        const float x = wseg[c];
        if (x > T) { const float u = 1.0f + x; s += u * u; ++g; }
    }
    #pragma unroll
    for (int off = 32; off > 0; off >>= 1) {
        s += __shfl_down(s, off);
        g += __shfl_down(g, off);
    }
    if (lane == 0) { s_fpart[wid] = s; s_ipart[wid] = g; }
    __syncthreads();
    if (tid == 0) {
        float ss = s_fpart[0] + s_fpart[1] + s_fpart[2] + s_fpart[3];
        int   gg = s_ipart[0] + s_ipart[1] + s_ipart[2] + s_ipart[3];
        if (pos_in && pos_v > T) {     // exact removal of the positive column
            const float u = 1.0f + pos_v;
            ss -= u * u;
            gg -= 1;
        }
        const float uT = 1.0f + T;
        const float neg = (ss + (float)(KSEL - gg) * uT * uT) / (float)KSEL;
        const float d = 1.0f - pos_v;
        row_loss[row] = DELTA_C * d * d + neg;
    }
}

__global__ __launch_bounds__(1024) void reduce_kernel(
    const float* __restrict__ row_loss, float* __restrict__ out)
{
    __shared__ float s[1024];
    float acc = 0.0f;
    for (int i = threadIdx.x; i < M_ROWS; i += 1024) acc += row_loss[i];
    s[threadIdx.x] = acc;
    __syncthreads();
    for (int off = 512; off > 0; off >>= 1) {
        if (threadIdx.x < off) s[threadIdx.x] += s[threadIdx.x + off];
        __syncthreads();
    }
    if (threadIdx.x == 0) out[0] = s[0] / (float)M_ROWS;
}

extern "C" void kernel_launch(void* const* d_in, const int* in_sizes, int n_in,
                              void* d_out, int out_size, void* d_ws, size_t ws_size,
                              hipStream_t stream) {
    const float* inputs  = (const float*)d_in[0];
    // d_in[1] = targets_ (unused by reference), d_in[3] = GT_MC (unused)
    const int*   targets = (const int*)d_in[2];
    float* row_loss = (float*)d_ws;   // 4096 floats = 16 KB scratch

    row_loss_kernel<<<M_ROWS, BLOCK, 0, stream>>>(inputs, targets, row_loss);
    reduce_kernel<<<1, 1024, 0, stream>>>(row_loss, (float*)d_out);
}

// Round 9
// 41.476 us; speedup vs baseline: 3.0651x; 1.0198x over previous
//
#include <hip/hip_runtime.h>
#include <cstdint>

// MMCL loss: per-row top-K hard negatives.
// M=4096 rows, N=13000 cols fp32; K = int(0.01*(N-1)) = 129.
// loss_row = 5*(1-pos)^2 + mean_{topK negatives}((1+v)^2); output = mean over rows.
//
// One 256-thread block per row.
// Streaming (R4-proven): 4x-unrolled, 4 float4 loads hoisted per iter,
// candidates > t0=2.0 (~296/row for N(0,1)) ballot-compacted into per-wave
// LDS segments (wave-uniform counter, no atomics in the hot loop). One
// barrier per pass on the common path (second barrier only if another pass
// is needed).
// Selection (R7/R8-proven exact): post-stream 256-bucket value histogram
// (bucket = clamp((x-2)*64)); one wave suffix-scans it (shfl only) to locate
// the bucket holding the K-th largest negative + within-bucket rank; bucket
// elements gathered; exact T rank-selected from raw values. Positive column
// streams like any value and is exactly removed via uniform corrections
// (histogram / rank-skip / final sum).
// loss = [sum_{v>T}(1+v)^2 + (K-cnt)*(1+T)^2]/K (exact under ties = lax.top_k).
// Fallbacks (never taken for this data, kept for exactness): gather overflow
// -> 8-pass 4-bit radix select; segment under/overflow -> threshold bisection
// in sortable-key space.
// Per-row losses -> d_ws; small 256-thread float4 reduce kernel does the
// deterministic mean. (R7 measured: single-address global atomicAdd from
// 4096 blocks costs ~25 us cross-XCD — do not fuse the mean via one atomic.)

constexpr int M_ROWS = 4096;
constexpr int N_COLS = 13000;
constexpr int N4     = N_COLS / 4;        // 3250 float4s (13000 % 4 == 0)
constexpr int KSEL   = 129;               // int(0.01 * 12999)
constexpr int BLOCK  = 256;
constexpr int NWAVE  = BLOCK / 64;        // 4
constexpr int WCAP   = 320;               // per-wave candidate cap (~74 expected)
constexpr int GCAP   = 64;                // bucket-gather cap (~5-11 expected)
constexpr int FULL_IT  = N4 / (4 * BLOCK);        // 3
constexpr int TAIL_BASE = FULL_IT * 4 * BLOCK;    // 3072
constexpr int TAIL_N    = N4 - TAIL_BASE;         // 178
constexpr float DELTA_C = 5.0f;
constexpr float T0   = 2.0f;

// monotone float -> uint32 key (larger float => larger key)
__device__ __forceinline__ uint32_t f2key(float f) {
    uint32_t u = __float_as_uint(f);
    return u ^ ((u & 0x80000000u) ? 0xFFFFFFFFu : 0x80000000u);
}
__device__ __forceinline__ float key2f(uint32_t k) {
    uint32_t u = (k & 0x80000000u) ? (k ^ 0x80000000u) : ~k;
    return __uint_as_float(u);
}
__device__ __forceinline__ int bucketof(float x) {
    int i = (int)((x - 2.0f) * 64.0f);
    return i < 0 ? 0 : (i > 255 ? 255 : i);
}

__global__ __launch_bounds__(BLOCK) void row_loss_kernel(
    const float* __restrict__ inputs,
    const int*   __restrict__ targets,
    float*       __restrict__ row_loss)
{
    __shared__ float cand[NWAVE * WCAP];   // per-wave segments
    __shared__ int   s_wcnt[NWAVE];
    __shared__ int   s_hist[256];          // value-bucket hist (16 reused by fallback)
    __shared__ float s_gath[GCAP];
    __shared__ int   s_gcnt;
    __shared__ int   s_bkt, s_need;
    __shared__ float s_T;
    __shared__ float s_fpart[NWAVE];
    __shared__ int   s_ipart[NWAVE];
    __shared__ int   s_rb, s_rn;           // fallback radix bucket/need

    const int row  = blockIdx.x;
    const int tid  = threadIdx.x;
    const int wid  = tid >> 6;
    const int lane = tid & 63;
    const float* rp = inputs + (size_t)row * N_COLS;
    const float4* rp4 = reinterpret_cast<const float4*>(rp);
    const int pos = targets[row];
    const float pos_v = rp[pos];           // uniform broadcast load
    const uint64_t below = (1ull << lane) - 1ull;
    float* wseg = cand + wid * WCAP;

    // one full streaming pass at threshold t; returns wave-uniform match count
    auto stream_pass = [&](float t) -> int {
        int wcnt = 0;
        auto proc = [&](float x) {
            const uint64_t m = __ballot(x > t);
            if (x > t) {
                const int slot = wcnt + (int)__popcll(m & below);
                if (slot < WCAP) wseg[slot] = x;
            }
            wcnt += (int)__popcll(m);                  // wave-uniform add
        };
        for (int it = 0; it < FULL_IT; ++it) {         // 3 iters
            const int b = it * 4 * BLOCK + tid;
            const float4 v0 = rp4[b];
            const float4 v1 = rp4[b +     BLOCK];
            const float4 v2 = rp4[b + 2 * BLOCK];
            const float4 v3 = rp4[b + 3 * BLOCK];
            proc(v0.x); proc(v0.y); proc(v0.z); proc(v0.w);
            proc(v1.x); proc(v1.y); proc(v1.z); proc(v1.w);
            proc(v2.x); proc(v2.y); proc(v2.z); proc(v2.w);
            proc(v3.x); proc(v3.y); proc(v3.z); proc(v3.w);
        }
        // branchless tail: sentinel keeps ballot wave-uniform, never matches
        const float4 vt = (tid < TAIL_N) ? rp4[TAIL_BASE + tid]
                                         : make_float4(-1e30f, -1e30f, -1e30f, -1e30f);
        proc(vt.x); proc(vt.y); proc(vt.z); proc(vt.w);
        return wcnt;
    };

    // ---- candidate collection (common case: one pass at t = 2.0) ----
    uint32_t keyA = 0u, keyB = 0xFFFFFFFFu;
    float t = T0;
    bool collapsed = false;       // K-th largest negative known exactly (Tval)
    float Tval = 0.0f;
    int cnt = 0;                  // this wave's candidate count (uniform)

    for (int iter = 0; iter < 64; ++iter) {
        cnt = stream_pass(t);
        if (lane == 0) s_wcnt[wid] = cnt;
        __syncthreads();
        const int c0 = s_wcnt[0], c1 = s_wcnt[1], c2 = s_wcnt[2], c3 = s_wcnt[3];
        const int total = c0 + c1 + c2 + c3;
        const bool ovf = (c0 > WCAP) | (c1 > WCAP) | (c2 > WCAP) | (c3 > WCAP);
        const int npos = (pos_v > t) ? 1 : 0;   // positive inside candidates?

        if (collapsed || (!ovf && (total - npos) >= KSEL)) break;   // common path

        const uint32_t kt = f2key(t);
        if (ovf) keyA = kt; else keyB = kt;
        if (keyB - keyA <= 1u) {
            Tval = key2f(keyB);      // exact: #{x > Tval} < K <= #{x >= Tval}
            t = Tval;
            collapsed = true;
        } else {
            t = key2f(keyA + (keyB - keyA) / 2u);
        }
        __syncthreads();             // fallback path only: protect s_wcnt reuse
    }

    const int mycnt = cnt < WCAP ? cnt : WCAP;     // wave-uniform
    const uint32_t key_pos = f2key(pos_v);
    const bool pos_in = (pos_v > t);   // positive present in candidate multiset

    float T;
    if (collapsed) {
        T = Tval;   // candidates are exactly {v > T}, negative count < K
    } else {
        // ---- build 256-bucket value histogram from segments (one pass) ----
        s_hist[tid] = 0;                  // BLOCK==256: one bucket each
        if (tid == 0) s_gcnt = 0;
        __syncthreads();
        for (int c = lane; c < mycnt; c += 64)     // wave scans own segment
            atomicAdd(&s_hist[bucketof(wseg[c])], 1);
        __syncthreads();

        // ---- pick bucket holding the K-th largest negative (1 wave) ----
        if (wid == 0) {
            int h[4];
            #pragma unroll
            for (int k = 0; k < 4; ++k) {
                h[k] = s_hist[4 * lane + k];
                if (pos_in && bucketof(pos_v) == 4 * lane + k) h[k] -= 1;
            }
            const int G = h[0] + h[1] + h[2] + h[3];
            int x = G;                        // inclusive suffix sum over lanes
            #pragma unroll
            for (int off = 1; off < 64; off <<= 1) {
                const int tmp = __shfl_down(x, off);
                if (lane + off < 64) x += tmp;
            }
            const int xnext = x - G;          // suffix starting at 4*lane+4
            const int cc3 = xnext + h[3];
            const int cc2 = cc3 + h[2];
            const int cc1 = cc2 + h[1];
            if (x >= KSEL && xnext < KSEL) {  // exactly one lane hits this
                int k, Cnext;
                if      (cc3 >= KSEL) { k = 3; Cnext = xnext; }
                else if (cc2 >= KSEL) { k = 2; Cnext = cc3; }
                else if (cc1 >= KSEL) { k = 1; Cnext = cc2; }
                else                  { k = 0; Cnext = cc1; }
                s_bkt = 4 * lane + k;
                s_need = KSEL - Cnext;        // rank within bucket, from top
            }
        }
        __syncthreads();
        const int bsel = s_bkt;
        const int need = s_need;

        // ---- gather that bucket's elements from all segments ----
        for (int c = lane; c < mycnt; c += 64) {
            const float x = wseg[c];
            if (bucketof(x) == bsel) {
                const int slot = atomicAdd(&s_gcnt, 1);
                if (slot < GCAP) s_gath[slot] = x;
            }
        }
        __syncthreads();
        const int m = s_gcnt;

        if (m <= GCAP) {
            // ---- exact rank-select of T among <=64 raw values (1 wave) ----
            if (wid == 0) {
                int skip = -1;
                if (pos_in && bucketof(pos_v) == bsel) {
                    const bool eq = (lane < m) &&
                        (__float_as_uint(s_gath[lane]) == __float_as_uint(pos_v));
                    const uint64_t em = __ballot(eq);
                    if (em) skip = __ffsll((long long)em) - 1;
                }
                const bool valid = (lane < m) && (lane != skip);
                const float x = valid ? s_gath[lane] : 0.0f;
                int g = 0, ge = 0;
                for (int j = 0; j < m; ++j) {
                    const float y = s_gath[j];       // broadcast read
                    const bool vj = (j != skip);
                    g  += (vj && y >  x);
                    ge += (vj && y >= x);
                }
                if (valid && g < need && ge >= need) s_T = x;  // unique value
            }
            __syncthreads();
            T = s_T;
        } else {
            // ---- fallback: 8-pass 4-bit radix select over segments ----
            uint32_t hi = 0;
            int need2 = KSEL;
            for (int shift = 28; shift >= 0; shift -= 4) {
                if (tid < 16) s_hist[tid] = 0;
                __syncthreads();
                const uint32_t maskHigh = (uint32_t)(0xFFFFFFFFull << (shift + 4));
                for (int c = lane; c < mycnt; c += 64) {
                    const uint32_t k = f2key(wseg[c]);
                    if ((k & maskHigh) == hi)
                        atomicAdd(&s_hist[(k >> shift) & 15], 1);
                }
                __syncthreads();
                if (tid == 0) {
                    if (pos_in && ((key_pos & maskHigh) == hi))
                        s_hist[(key_pos >> shift) & 15] -= 1;
                    int cum = 0, b = 15;
                    for (; b > 0; --b) {
                        const int h = s_hist[b];
                        if (cum + h >= need2) break;
                        cum += h;
                    }
                    s_rb = b;
                    s_rn = need2 - cum;
                }
                __syncthreads();
                hi |= ((uint32_t)s_rb) << shift;
                need2 = s_rn;
            }
            T = key2f(hi);
        }
    }

    // ---- sum f(v)=(1+v)^2 over v > T, pad with (K-cnt) copies of f(T) ----
    float s = 0.0f;
    int g = 0;
    for (int c = lane; c < mycnt; c += 64) {
        const float x = wseg[c];
        if (x > T) { const float u = 1.0f + x; s += u * u; ++g; }
    }
    #pragma unroll
    for (int off = 32; off > 0; off >>= 1) {
        s += __shfl_down(s, off);
        g += __shfl_down(g, off);
    }
    if (lane == 0) { s_fpart[wid] = s; s_ipart[wid] = g; }
    __syncthreads();
    if (tid == 0) {
        float ss = s_fpart[0] + s_fpart[1] + s_fpart[2] + s_fpart[3];
        int   gg = s_ipart[0] + s_ipart[1] + s_ipart[2] + s_ipart[3];
        if (pos_in && pos_v > T) {     // exact removal of the positive column
            const float u = 1.0f + pos_v;
            ss -= u * u;
            gg -= 1;
        }
        const float uT = 1.0f + T;
        const float neg = (ss + (float)(KSEL - gg) * uT * uT) / (float)KSEL;
        const float d = 1.0f - pos_v;
        row_loss[row] = DELTA_C * d * d + neg;
    }
}

// 4096 floats = 1024 float4s; 256 threads x 4 float4 each, fixed order.
__global__ __launch_bounds__(256) void reduce_kernel(
    const float* __restrict__ row_loss, float* __restrict__ out)
{
    __shared__ float s_p[4];
    const int tid  = threadIdx.x;
    const int wid  = tid >> 6;
    const int lane = tid & 63;
    const float4* rl4 = reinterpret_cast<const float4*>(row_loss);
    float acc = 0.0f;
    #pragma unroll
    for (int j = 0; j < 4; ++j) {
        const float4 v = rl4[tid + j * 256];
        acc += (v.x + v.y) + (v.z + v.w);
    }
    #pragma unroll
    for (int off = 32; off > 0; off >>= 1) acc += __shfl_down(acc, off);
    if (lane == 0) s_p[wid] = acc;
    __syncthreads();
    if (tid == 0)
        out[0] = ((s_p[0] + s_p[1]) + (s_p[2] + s_p[3])) / (float)M_ROWS;
}

extern "C" void kernel_launch(void* const* d_in, const int* in_sizes, int n_in,
                              void* d_out, int out_size, void* d_ws, size_t ws_size,
                              hipStream_t stream) {
    const float* inputs  = (const float*)d_in[0];
    // d_in[1] = targets_ (unused by reference), d_in[3] = GT_MC (unused)
    const int*   targets = (const int*)d_in[2];
    float* row_loss = (float*)d_ws;   // 4096 floats = 16 KB scratch

    row_loss_kernel<<<M_ROWS, BLOCK, 0, stream>>>(inputs, targets, row_loss);
    reduce_kernel<<<1, 256, 0, stream>>>(row_loss, (float*)d_out);
}